// Round 10
// baseline (348.118 us; speedup 1.0000x reference)
//
#include <hip/hip_runtime.h>
#include <hip/hip_cooperative_groups.h>

namespace cg = cooperative_groups;

// Problem constants
#define ARW_N_NODES   100000
#define ARW_N_EDGES   3200000
#define ARW_N_WALKERS 400000
#define ARW_WLEN      8
#define ARW_LOUT      7
#define ARW_ROW_LEN   6000000           // N_EDGES + N_WALKERS*LOUT
#define ARW_OUT_ELEMS 18000000          // float32 output elements

// Sort geometry: 256 buckets of 392 rows (b = r/392); 782 tiles of 4096 edges.
// Whole sort chain fused into ONE cooperative kernel (256 blocks = 1/CU):
//   A: tile hists -> gsync -> B: per-bucket tile scan + tot -> gsync ->
//   C: cb scan (replicated in LDS, bbase deleted) -> D: partition ->
//   gsync -> E: per-bucket stable scatter (pass2).
#define ARW_NB    256
#define ARW_RPB   392
#define ARW_NT    782
#define ARW_TP    784                  // padded t-stride for Bt (b-major)
#define ARW_TILE  4096
#define ARW_PMAX  14336                // phase-E LDS P-stage capacity (bucket max ~13.0K)

// Scratch inside d_out (18M floats = 72MB), int32 view; staged lifetimes:
//   Ht  @ [0, 200192)          histograms, T-MAJOR: Ht[t][b] = HT + t*256 + b
//   Bt  @ [900000, 1100672)    bucket-LOCAL scan bases Bt[b][t] = BT + b*TP + t
//   tot @ [1750000, +256)      per-bucket totals (phase B)
//   pd  @ [1800000, 1900000)   packed (rowptr<<10 | deg), written by phase E
//   P   @ [6000000, 9200000)   packed partition (dead after phase E; walk's fused
//                              row1-copy overwrites it)
//   col_s @ [12000000, 15200000) (weights region; asm overwrites after walk)
// walk writes: targets [9200000,12000000), roots [3200000,6000000),
//              row1-originals [6000000,9200000).
// asm (last) writes [0,3200000) + [12000000,18000000).
#define ARW_HT    0
#define ARW_BT    900000
#define ARW_TOT   1750000
#define ARW_PD    1800000
#define ARW_P     6000000
#define ARW_COLS  12000000

__global__ void AddRandomWalkEdge_16896401342869_kernel() {}

// ---------- 1. fused sort chain (cooperative, 256 blocks x 1024 thr) ----------
__global__ __launch_bounds__(1024) void arw16896_fused(const int* __restrict__ row,
                                                       const int* __restrict__ col,
                                                       int* __restrict__ s) {
    cg::grid_group grid = cg::this_grid();
    __shared__ union {
        int h[256];                                                  // phase A
        struct { unsigned short W[16 * 256]; int runc[256]; int lbase[256]; } d;  // phase D
        struct { int PL[ARW_PMAX]; unsigned short W[16 * 512];
                 int hist[512], pref[512], runc[512]; } e;           // phase E (~78KB)
    } U;
    __shared__ int cbL[257];
    __shared__ int wsum[16];
    int tid = threadIdx.x, lane = tid & 63, wave = tid >> 6;
    int bid = blockIdx.x;

    // ---- Phase A: tile histograms (t-major coalesced out) ----
    for (int t = bid; t < ARW_NT; t += ARW_NB) {
        if (tid < 256) U.h[tid] = 0;
        __syncthreads();
        #pragma unroll
        for (int rnd = 0; rnd < 4; rnd++) {
            int e = t * ARW_TILE + rnd * 1024 + tid;
            if (e < ARW_N_EDGES) atomicAdd(&U.h[row[e] / ARW_RPB], 1);
        }
        __syncthreads();
        if (tid < 256) s[ARW_HT + t * 256 + tid] = U.h[tid];
        __syncthreads();
    }
    grid.sync();

    // ---- Phase B: per-bucket exclusive scan over 782 tiles + total ----
    {
        int v = (tid < ARW_NT) ? s[ARW_HT + tid * 256 + bid] : 0;
        int sv = v;
        #pragma unroll
        for (int off = 1; off < 64; off <<= 1) {
            int x = __shfl_up(sv, off, 64);
            if (lane >= off) sv += x;
        }
        if (lane == 63) wsum[wave] = sv;
        __syncthreads();
        int pre = 0, tot = 0;
        #pragma unroll
        for (int w = 0; w < 16; w++) {
            int x = wsum[w];
            if (w < wave) pre += x;
            tot += x;
        }
        if (tid < ARW_NT) s[ARW_BT + bid * ARW_TP + tid] = pre + sv - v;
        if (tid == 0) s[ARW_TOT + bid] = tot;
    }
    grid.sync();

    // ---- Phase C: replicated 256-bucket exclusive scan -> cbL (bbase deleted) ----
    {
        int v = (tid < 256) ? s[ARW_TOT + tid] : 0;
        if (tid < 256) cbL[tid] = v;
        __syncthreads();
        for (int off = 1; off < 256; off <<= 1) {
            int x = 0;
            if (tid < 256 && tid >= off) x = cbL[tid - off];
            __syncthreads();
            if (tid < 256) cbL[tid] += x;
            __syncthreads();
        }
        if (tid < 256) cbL[tid] -= v;
        if (tid == 0) cbL[256] = ARW_N_EDGES;
        __syncthreads();
    }

    // ---- Phase D: stable partition, 4096-edge tiles (4 rounds + running cursor) ----
    for (int t = bid; t < ARW_NT; t += ARW_NB) {
        if (tid < 256) {
            U.d.runc[tid]  = 0;
            U.d.lbase[tid] = cbL[tid] + s[ARW_BT + tid * ARW_TP + t];
        }
        __syncthreads();
        #pragma unroll
        for (int rnd = 0; rnd < 4; rnd++) {
            int e = t * ARW_TILE + rnd * 1024 + tid;
            int valid = (e < ARW_N_EDGES) ? 1 : 0;
            int r = valid ? row[e] : 0;
            int cv = valid ? col[e] : 0;
            int b = r / ARW_RPB;                 // magic-mul division
            int lr = r - b * ARW_RPB;            // 9 bits (<392)
            #pragma unroll
            for (int j = 0; j < 4; j++) U.d.W[tid + j * 1024] = 0;
            __syncthreads();
            unsigned long long mask = ~0ULL;
            #pragma unroll
            for (int bit = 0; bit < 8; bit++) {
                unsigned long long bal = __ballot((b >> bit) & 1);
                mask &= ((b >> bit) & 1) ? bal : ~bal;
            }
            mask &= __ballot(valid);
            int rankw = __popcll(mask & ((1ULL << lane) - 1ULL));
            if (valid) U.d.W[wave * 256 + b] = (unsigned short)__popcll(mask);
            __syncthreads();
            if (valid) {
                int cross = 0;
                for (int w2 = 0; w2 < 16; w2++) {
                    if (w2 >= wave) break;
                    cross += (int)U.d.W[w2 * 256 + b];
                }
                s[ARW_P + U.d.lbase[b] + U.d.runc[b] + cross + rankw] = (lr << 17) | cv;
            }
            __syncthreads();
            if (tid < 256) {
                int a = 0;
                #pragma unroll
                for (int w = 0; w < 16; w++) a += (int)U.d.W[w * 256 + tid];
                U.d.runc[tid] += a;
            }
            __syncthreads();
        }
    }
    grid.sync();

    // ---- Phase E: per-bucket stable scatter -> col_s + packed pd ----
    {
        int b = bid;
        int start = cbL[b];
        int end   = cbL[b + 1];
        int cnt = end - start;
        int staged = cnt < ARW_PMAX ? cnt : ARW_PMAX;   // overflow ~16 sigma; guarded
        int rows0 = b * ARW_RPB;
        int nrows = ARW_N_NODES - rows0; if (nrows > ARW_RPB) nrows = ARW_RPB;

        for (int k = tid; k < staged; k += 1024) U.e.PL[k] = s[ARW_P + start + k];
        if (tid < 512) U.e.hist[tid] = 0;
        __syncthreads();

        // Pass A: histogram (from LDS)
        for (int k = tid; k < cnt; k += 1024) {
            unsigned p = (unsigned)(k < staged ? U.e.PL[k] : s[ARW_P + start + k]);
            atomicAdd(&U.e.hist[p >> 17], 1);
        }
        __syncthreads();
        if (tid < 512) U.e.pref[tid] = U.e.hist[tid];
        __syncthreads();
        for (int off = 1; off < 512; off <<= 1) {     // inclusive scan of hist
            int x = 0;
            if (tid < 512 && tid >= off) x = U.e.pref[tid - off];
            __syncthreads();
            if (tid < 512) U.e.pref[tid] += x;
            __syncthreads();
        }
        if (tid < 512) U.e.runc[tid] = 0;
        if (tid < nrows) {
            // packed (rowptr<<10 | deg). rowptr < 3.2M (22b); deg Poisson(32) << 1023.
            unsigned deg = (unsigned)U.e.hist[tid];
            unsigned rp  = (unsigned)(start + U.e.pref[tid] - U.e.hist[tid]);
            s[ARW_PD + rows0 + tid] = (int)((rp << 10) | deg);
        }
        __syncthreads();

        // Pass B: stable scatter (reads LDS)
        for (int c0 = 0; c0 < cnt; c0 += 1024) {
            int k = c0 + tid;
            int valid = (k < cnt) ? 1 : 0;
            unsigned p = 0u;
            if (valid) p = (unsigned)(k < staged ? U.e.PL[k] : s[ARW_P + start + k]);
            unsigned lr = p >> 17;                     // 9 bits
            #pragma unroll
            for (int j = 0; j < 8; j++) U.e.W[tid + j * 1024] = 0;
            __syncthreads();
            unsigned long long mask = ~0ULL;
            #pragma unroll
            for (int bit = 0; bit < 9; bit++) {
                unsigned long long bal = __ballot((lr >> bit) & 1u);
                mask &= ((lr >> bit) & 1u) ? bal : ~bal;
            }
            mask &= __ballot(valid);
            int rankw = __popcll(mask & ((1ULL << lane) - 1ULL));
            if (valid) U.e.W[wave * 512 + lr] = (unsigned short)__popcll(mask);
            __syncthreads();
            if (valid) {
                int cross = 0;
                for (int w2 = 0; w2 < 16; w2++) {
                    if (w2 >= wave) break;
                    cross += (int)U.e.W[w2 * 512 + lr];
                }
                int pos = start + (U.e.pref[lr] - U.e.hist[lr]) + U.e.runc[lr] + cross + rankw;
                s[ARW_COLS + pos] = (int)(p & 0x1FFFFu);
            }
            __syncthreads();
            if (tid < 512) {
                int a = 0;
                #pragma unroll
                for (int w = 0; w < 16; w++) a += (int)U.e.W[w * 512 + tid];
                U.e.runc[tid] += a;
            }
            __syncthreads();
        }
    }
}

// ---------- 2. walks (256 thr) + fused streaming tail ----------
// Walk is miss-throughput bound (~36% HBM BW, VALU 3%): idle BW absorbs the
// row1-originals copy ([6M,9.2M), over dead P) and the roots fill ([3.2M,6M)).
__global__ __launch_bounds__(256) void arw16896_walk(const float* __restrict__ ru,
                                                     const int* __restrict__ ei,
                                                     const int* __restrict__ s,
                                                     float* __restrict__ o) {
    __shared__ float tg[4 * 256 * ARW_LOUT];   // 28 KB: 4 segments of 256x7
    int tid = threadIdx.x;
    int v = blockIdx.x * 256 + tid;
    if (v < ARW_N_NODES) {
        float uu[4][8];
        int cur[4];
        #pragma unroll
        for (int k = 0; k < 4; k++) {
            const float4* rp4 = (const float4*)(ru + (size_t)(v + k * ARW_N_NODES) * 8);
            float4 ra = rp4[0], rb = rp4[1];
            uu[k][0] = ra.x; uu[k][1] = ra.y; uu[k][2] = ra.z; uu[k][3] = ra.w;
            uu[k][4] = rb.x; uu[k][5] = rb.y; uu[k][6] = rb.z; uu[k][7] = rb.w;
        }
        // step 0: all 4 walkers share pd[v]; col loads hit the same row segment
        unsigned pd0 = (unsigned)s[ARW_PD + v];
        int d0  = (int)(pd0 & 1023u);
        int rp0 = (int)(pd0 >> 10);
        #pragma unroll
        for (int k = 0; k < 4; k++) {
            int off = (int)(uu[k][0] * (float)d0);   // f32 mul + trunc == reference
            if (off > d0 - 1) off = d0 - 1;
            int nxt = s[ARW_COLS + rp0 + off];       // off=-1 only if d0==0: in-bounds junk
            cur[k] = (d0 > 0) ? nxt : v;
        }
        // steps 1..7: 4 independent chains; batch the 4 pd loads, then 4 col loads
        #pragma unroll
        for (int t = 1; t < ARW_WLEN; t++) {
            unsigned pdk[4];
            #pragma unroll
            for (int k = 0; k < 4; k++) pdk[k] = (unsigned)s[ARW_PD + cur[k]];
            #pragma unroll
            for (int k = 0; k < 4; k++) {
                int d = (int)(pdk[k] & 1023u);
                int off = (int)(uu[k][t] * (float)d);
                if (off > d - 1) off = d - 1;        // d==0 -> off=-1, load stays in-bounds
                int nxt = s[ARW_COLS + (int)(pdk[k] >> 10) + off];
                cur[k] = (d > 0) ? nxt : cur[k];
                tg[k * (256 * ARW_LOUT) + tid * ARW_LOUT + (t - 1)] = (float)cur[k];
            }
        }
    }
    __syncthreads();
    int blkN = ARW_N_NODES - blockIdx.x * 256;
    if (blkN > 256) blkN = 256;
    int valid = blkN * ARW_LOUT;
    #pragma unroll
    for (int k = 0; k < 4; k++) {
        int base = ARW_ROW_LEN + ARW_N_EDGES +
                   (k * ARW_N_NODES + blockIdx.x * 256) * ARW_LOUT;
        for (int j = tid; j < valid; j += 256)
            o[base + j] = tg[k * (256 * ARW_LOUT) + j];
    }
    // fused streaming tail (grid-stride over all walk threads)
    int gid = blockIdx.x * 256 + tid;
    int stride = gridDim.x * 256;
    for (int i4 = gid; i4 < ARW_N_EDGES / 4; i4 += stride) {
        int4 r1 = ((const int4*)(ei + ARW_N_EDGES))[i4];
        ((float4*)(o + ARW_ROW_LEN))[i4] =
            make_float4((float)r1.x, (float)r1.y, (float)r1.z, (float)r1.w);
    }
    for (int i4 = gid; i4 < (ARW_N_WALKERS * ARW_LOUT) / 4; i4 += stride) {
        int i = i4 * 4;
        float4 r;
        r.x = (float)(((i    ) / ARW_LOUT) % ARW_N_NODES);
        r.y = (float)(((i + 1) / ARW_LOUT) % ARW_N_NODES);
        r.z = (float)(((i + 2) / ARW_LOUT) % ARW_N_NODES);
        r.w = (float)(((i + 3) / ARW_LOUT) % ARW_N_NODES);
        ((float4*)(o + ARW_N_EDGES))[i4] = r;
    }
}

// ---------- 3. remaining assembly: row0 originals + weights + ones ----------
__global__ __launch_bounds__(256) void arw16896_asm(const int* __restrict__ ei,
                                                    const float* __restrict__ wgt,
                                                    float* __restrict__ o) {
    int i4 = blockIdx.x * blockDim.x + threadIdx.x;
    if (i4 < ARW_N_EDGES / 4) {
        int4 r0 = ((const int4*)ei)[i4];
        float4 wv = ((const float4*)wgt)[i4];
        ((float4*)o)[i4] = make_float4((float)r0.x, (float)r0.y, (float)r0.z, (float)r0.w);
        ((float4*)(o + 2 * ARW_ROW_LEN))[i4] = wv;
    }
    if (i4 < (ARW_N_WALKERS * ARW_LOUT) / 4) {
        ((float4*)(o + 2 * ARW_ROW_LEN + ARW_N_EDGES))[i4] = make_float4(1.f, 1.f, 1.f, 1.f);
    }
}

extern "C" void kernel_launch(void* const* d_in, const int* in_sizes, int n_in,
                              void* d_out, int out_size, void* d_ws, size_t ws_size,
                              hipStream_t stream) {
    const int*   ei  = (const int*)d_in[0];
    const float* wgt = (const float*)d_in[1];
    const float* ru  = (const float*)d_in[2];
    int*   s = (int*)d_out;
    float* o = (float*)d_out;
    const int* row = ei;
    const int* col = ei + ARW_N_EDGES;

    void* fargs[] = { (void*)&row, (void*)&col, (void*)&s };
    hipLaunchCooperativeKernel(reinterpret_cast<void*>(arw16896_fused),
                               dim3(ARW_NB), dim3(1024), fargs, 0, stream);
    arw16896_walk <<<(ARW_N_NODES + 255) / 256, 256, 0, stream>>>(ru, ei, s, o);
    arw16896_asm  <<<(ARW_N_EDGES / 4 + 255) / 256, 256, 0, stream>>>(ei, wgt, o);
}

// Round 12
// 235.251 us; speedup vs baseline: 1.4798x; 1.4798x over previous
//
#include <hip/hip_runtime.h>

// Problem constants
#define ARW_N_NODES   100000
#define ARW_N_EDGES   3200000
#define ARW_N_WALKERS 400000
#define ARW_WLEN      8
#define ARW_LOUT      7
#define ARW_ROW_LEN   6000000           // N_EDGES + N_WALKERS*LOUT
#define ARW_OUT_ELEMS 18000000          // float32 output elements

// Sort geometry: 256 buckets of 392 rows (b = r/392); 782 tiles of 4096 edges.
#define ARW_NB    256
#define ARW_RPB   392
#define ARW_NT    782
#define ARW_TP    784                  // padded t-stride for Bt (b-major)
#define ARW_TILE  4096
#define ARW_PMAX  14336                // pass2 LDS P-stage capacity (bucket max ~13.0K)

// Scratch inside d_out (18M floats = 72MB), int32 view; staged lifetimes:
//   Ht  @ [0, 200192)          histograms, T-MAJOR: Ht[t][b] = HT + t*256 + b
//   Bt  @ [900000, 1100672)    bucket-LOCAL scan bases Bt[b][t] = BT + b*TP + t
//   tot @ [1750000, +256)      per-bucket totals (bscan2)
//   cb  @ [1760000, +256)      bucket exclusive bases (global)
//   pd  @ [1800000, 1900000)   packed (rowptr<<10 | deg), written by pass2
//   P   @ [6000000, 9200000)   packed partition (dead after pass2; walk's fused
//                              row1-copy overwrites it)
//   col_s @ [12000000, 15200000) (weights region; asm overwrites after walk)
// walk writes: targets [9200000,12000000), roots [3200000,6000000),
//              row1-originals [6000000,9200000).
// asm (last) writes [0,3200000) + [12000000,18000000).
#define ARW_HT    0
#define ARW_BT    900000
#define ARW_TOT   1750000
#define ARW_CB    1760000
#define ARW_PD    1800000
#define ARW_P     6000000
#define ARW_COLS  12000000

__global__ void AddRandomWalkEdge_16896401342869_kernel() {}

// ---------- 1. tile histogram: one 4096-tile/block, t-major coalesced output ----------
__global__ __launch_bounds__(1024) void arw16896_thist(const int* __restrict__ row,
                                                       int* __restrict__ s) {
    __shared__ int h[256];
    int tid = threadIdx.x, t = blockIdx.x;
    if (tid < 256) h[tid] = 0;
    __syncthreads();
    #pragma unroll
    for (int rnd = 0; rnd < 4; rnd++) {
        int e = t * ARW_TILE + rnd * 1024 + tid;
        if (e < ARW_N_EDGES) atomicAdd(&h[row[e] / ARW_RPB], 1);
    }
    __syncthreads();
    if (tid < 256) s[ARW_HT + t * 256 + tid] = h[tid];   // 1KB contiguous run
}

// ---------- 2a. per-bucket exclusive scan over 782 tiles (single chunk) + total ----------
__global__ __launch_bounds__(1024) void arw16896_bscan2(int* __restrict__ s) {
    __shared__ int wsum[16];
    int b = blockIdx.x, tid = threadIdx.x, lane = tid & 63, wid = tid >> 6;
    int v = (tid < ARW_NT) ? s[ARW_HT + tid * 256 + b] : 0;   // t-major gather (L2)
    int sv = v;
    #pragma unroll
    for (int off = 1; off < 64; off <<= 1) {
        int x = __shfl_up(sv, off, 64);
        if (lane >= off) sv += x;
    }
    if (lane == 63) wsum[wid] = sv;
    __syncthreads();
    int pre = 0, tot = 0;
    #pragma unroll
    for (int w = 0; w < 16; w++) {
        int x = wsum[w];
        if (w < wid) pre += x;
        tot += x;
    }
    if (tid < ARW_NT) s[ARW_BT + b * ARW_TP + tid] = pre + sv - v;  // bucket-local
    if (tid == 0) s[ARW_TOT + b] = tot;
}

// ---------- 2b. exclusive scan of 256 bucket totals (1 block) -> cb ----------
__global__ __launch_bounds__(256) void arw16896_bbase(int* __restrict__ s) {
    __shared__ int sm[256];
    int tid = threadIdx.x;
    int v = s[ARW_TOT + tid];
    sm[tid] = v;
    __syncthreads();
    for (int off = 1; off < 256; off <<= 1) {
        int x = 0;
        if (tid >= off) x = sm[tid - off];
        __syncthreads();
        sm[tid] += x;
        __syncthreads();
    }
    s[ARW_CB + tid] = sm[tid] - v;
}

// ---------- 3. stable partition, 4096-edge tiles; W pre-scanned to bases ----------
// Leaders publish group counts into W2; threads tid<256 scan the 16 wave-columns
// in place (conflict-free stride-256), folding in lbase+runc and updating runc.
// Each valid lane then does ONE gather W2[wave][b] (was: 15 serial conflicted
// gathers per thread -- the 4.86M SQ_LDS_BANK_CONFLICT hotspot).
__global__ __launch_bounds__(1024) void arw16896_part(const int* __restrict__ row,
                                                      const int* __restrict__ col,
                                                      int* __restrict__ s) {
    __shared__ int W2[16 * 256];          // 16 KB: counts -> absolute bases
    __shared__ int runc[256], lbase[256];
    int tid  = threadIdx.x;
    int wave = tid >> 6, lane = tid & 63;
    int t = blockIdx.x;
    if (tid < 256) {
        runc[tid]  = 0;
        lbase[tid] = s[ARW_CB + tid] + s[ARW_BT + tid * ARW_TP + t];
    }
    __syncthreads();
    #pragma unroll
    for (int rnd = 0; rnd < 4; rnd++) {
        int e = t * ARW_TILE + rnd * 1024 + tid;
        int valid = (e < ARW_N_EDGES) ? 1 : 0;
        int r = valid ? row[e] : 0;
        int cv = valid ? col[e] : 0;
        int b = r / ARW_RPB;                 // magic-mul division
        int lr = r - b * ARW_RPB;            // 9 bits (<392)
        #pragma unroll
        for (int j = 0; j < 4; j++) W2[tid + j * 1024] = 0;
        __syncthreads();
        unsigned long long mask = ~0ULL;
        #pragma unroll
        for (int bit = 0; bit < 8; bit++) {
            unsigned long long bal = __ballot((b >> bit) & 1);
            mask &= ((b >> bit) & 1) ? bal : ~bal;
        }
        mask &= __ballot(valid);
        int rankw = __popcll(mask & ((1ULL << lane) - 1ULL));
        int leader = __ffsll(mask) - 1;
        if (valid && lane == leader) W2[wave * 256 + b] = __popcll(mask);
        __syncthreads();
        if (tid < 256) {
            int acc = lbase[tid] + runc[tid];
            #pragma unroll
            for (int w = 0; w < 16; w++) {
                int c = W2[w * 256 + tid];
                W2[w * 256 + tid] = acc;
                acc += c;
            }
            runc[tid] = acc - lbase[tid];
        }
        __syncthreads();
        if (valid) s[ARW_P + W2[wave * 256 + b] + rankw] = (lr << 17) | cv;
        __syncthreads();
    }
}

// ---------- 4. per-bucket stable scatter -> col_s + packed pd ----------
// Same W2 pre-scan transform (512 rows x 16 waves); PL staging kept (R7-proven).
__global__ __launch_bounds__(1024) void arw16896_pass2(int* __restrict__ s) {
    __shared__ int PL[ARW_PMAX];              // 56 KB
    __shared__ int W2[16 * 512];              // 32 KB: counts -> absolute bases
    __shared__ int hist[512], pref[512], runc[512];
    int tid = threadIdx.x, lane = tid & 63, wave = tid >> 6;
    int b = blockIdx.x;
    int start = s[ARW_CB + b];
    int end   = (b == ARW_NB - 1) ? ARW_N_EDGES : s[ARW_CB + b + 1];
    int cnt = end - start;
    int staged = cnt < ARW_PMAX ? cnt : ARW_PMAX;   // overflow ~16 sigma; guarded
    int rows0 = b * ARW_RPB;
    int nrows = ARW_N_NODES - rows0; if (nrows > ARW_RPB) nrows = ARW_RPB;

    for (int k = tid; k < staged; k += 1024) PL[k] = s[ARW_P + start + k];
    if (tid < 512) hist[tid] = 0;
    __syncthreads();

    // Pass A: histogram (from LDS)
    for (int k = tid; k < cnt; k += 1024) {
        unsigned p = (unsigned)(k < staged ? PL[k] : s[ARW_P + start + k]);
        atomicAdd(&hist[p >> 17], 1);
    }
    __syncthreads();
    if (tid < 512) pref[tid] = hist[tid];
    __syncthreads();
    for (int off = 1; off < 512; off <<= 1) {     // inclusive scan of hist
        int x = 0;
        if (tid < 512 && tid >= off) x = pref[tid - off];
        __syncthreads();
        if (tid < 512) pref[tid] += x;
        __syncthreads();
    }
    if (tid < 512) runc[tid] = 0;
    if (tid < nrows) {
        // packed (rowptr<<10 | deg). rowptr < 3.2M (22 bits); deg Poisson(32) << 1023.
        unsigned deg = (unsigned)hist[tid];
        unsigned rp  = (unsigned)(start + pref[tid] - hist[tid]);
        s[ARW_PD + rows0 + tid] = (int)((rp << 10) | deg);
    }
    __syncthreads();

    // Pass B: stable scatter, one gather per edge
    for (int c0 = 0; c0 < cnt; c0 += 1024) {
        int k = c0 + tid;
        int valid = (k < cnt) ? 1 : 0;
        unsigned p = 0u;
        if (valid) p = (unsigned)(k < staged ? PL[k] : s[ARW_P + start + k]);
        unsigned lr = p >> 17;                     // 9 bits
        #pragma unroll
        for (int j = 0; j < 8; j++) W2[tid + j * 1024] = 0;
        __syncthreads();
        unsigned long long mask = ~0ULL;
        #pragma unroll
        for (int bit = 0; bit < 9; bit++) {
            unsigned long long bal = __ballot((lr >> bit) & 1u);
            mask &= ((lr >> bit) & 1u) ? bal : ~bal;
        }
        mask &= __ballot(valid);
        int rankw = __popcll(mask & ((1ULL << lane) - 1ULL));
        int leader = __ffsll(mask) - 1;
        if (valid && lane == leader) W2[wave * 512 + lr] = __popcll(mask);
        __syncthreads();
        if (tid < 512) {
            int rb = start + pref[tid] - hist[tid];
            int acc = rb + runc[tid];
            #pragma unroll
            for (int w = 0; w < 16; w++) {
                int c = W2[w * 512 + tid];
                W2[w * 512 + tid] = acc;
                acc += c;
            }
            runc[tid] = acc - rb;
        }
        __syncthreads();
        if (valid) s[ARW_COLS + W2[wave * 512 + lr] + rankw] = (int)(p & 0x1FFFFu);
        __syncthreads();
    }
}

// ---------- 5. walks (256 thr) + fused streaming tail ----------
// Walk is miss-throughput bound (~36% HBM BW, VALU 3%): idle BW absorbs the
// row1-originals copy ([6M,9.2M), over dead P) and the roots fill ([3.2M,6M)).
__global__ __launch_bounds__(256) void arw16896_walk(const float* __restrict__ ru,
                                                     const int* __restrict__ ei,
                                                     const int* __restrict__ s,
                                                     float* __restrict__ o) {
    __shared__ float tg[4 * 256 * ARW_LOUT];   // 28 KB: 4 segments of 256x7
    int tid = threadIdx.x;
    int v = blockIdx.x * 256 + tid;
    if (v < ARW_N_NODES) {
        float uu[4][8];
        int cur[4];
        #pragma unroll
        for (int k = 0; k < 4; k++) {
            const float4* rp4 = (const float4*)(ru + (size_t)(v + k * ARW_N_NODES) * 8);
            float4 ra = rp4[0], rb = rp4[1];
            uu[k][0] = ra.x; uu[k][1] = ra.y; uu[k][2] = ra.z; uu[k][3] = ra.w;
            uu[k][4] = rb.x; uu[k][5] = rb.y; uu[k][6] = rb.z; uu[k][7] = rb.w;
        }
        // step 0: all 4 walkers share pd[v]; col loads hit the same row segment
        unsigned pd0 = (unsigned)s[ARW_PD + v];
        int d0  = (int)(pd0 & 1023u);
        int rp0 = (int)(pd0 >> 10);
        #pragma unroll
        for (int k = 0; k < 4; k++) {
            int off = (int)(uu[k][0] * (float)d0);   // f32 mul + trunc == reference
            if (off > d0 - 1) off = d0 - 1;
            int nxt = s[ARW_COLS + rp0 + off];       // off=-1 only if d0==0: in-bounds junk
            cur[k] = (d0 > 0) ? nxt : v;
        }
        // steps 1..7: 4 independent chains; batch the 4 pd loads, then 4 col loads
        #pragma unroll
        for (int t = 1; t < ARW_WLEN; t++) {
            unsigned pdk[4];
            #pragma unroll
            for (int k = 0; k < 4; k++) pdk[k] = (unsigned)s[ARW_PD + cur[k]];
            #pragma unroll
            for (int k = 0; k < 4; k++) {
                int d = (int)(pdk[k] & 1023u);
                int off = (int)(uu[k][t] * (float)d);
                if (off > d - 1) off = d - 1;        // d==0 -> off=-1, load stays in-bounds
                int nxt = s[ARW_COLS + (int)(pdk[k] >> 10) + off];
                cur[k] = (d > 0) ? nxt : cur[k];
                tg[k * (256 * ARW_LOUT) + tid * ARW_LOUT + (t - 1)] = (float)cur[k];
            }
        }
    }
    __syncthreads();
    int blkN = ARW_N_NODES - blockIdx.x * 256;
    if (blkN > 256) blkN = 256;
    int valid = blkN * ARW_LOUT;
    #pragma unroll
    for (int k = 0; k < 4; k++) {
        int base = ARW_ROW_LEN + ARW_N_EDGES +
                   (k * ARW_N_NODES + blockIdx.x * 256) * ARW_LOUT;
        for (int j = tid; j < valid; j += 256)
            o[base + j] = tg[k * (256 * ARW_LOUT) + j];
    }
    // fused streaming tail (grid-stride over all walk threads)
    int gid = blockIdx.x * 256 + tid;
    int stride = gridDim.x * 256;
    for (int i4 = gid; i4 < ARW_N_EDGES / 4; i4 += stride) {
        int4 r1 = ((const int4*)(ei + ARW_N_EDGES))[i4];
        ((float4*)(o + ARW_ROW_LEN))[i4] =
            make_float4((float)r1.x, (float)r1.y, (float)r1.z, (float)r1.w);
    }
    for (int i4 = gid; i4 < (ARW_N_WALKERS * ARW_LOUT) / 4; i4 += stride) {
        int i = i4 * 4;
        float4 r;
        r.x = (float)(((i    ) / ARW_LOUT) % ARW_N_NODES);
        r.y = (float)(((i + 1) / ARW_LOUT) % ARW_N_NODES);
        r.z = (float)(((i + 2) / ARW_LOUT) % ARW_N_NODES);
        r.w = (float)(((i + 3) / ARW_LOUT) % ARW_N_NODES);
        ((float4*)(o + ARW_N_EDGES))[i4] = r;
    }
}

// ---------- 6. remaining assembly: row0 originals + weights + ones ----------
__global__ __launch_bounds__(256) void arw16896_asm(const int* __restrict__ ei,
                                                    const float* __restrict__ wgt,
                                                    float* __restrict__ o) {
    int i4 = blockIdx.x * blockDim.x + threadIdx.x;
    if (i4 < ARW_N_EDGES / 4) {
        int4 r0 = ((const int4*)ei)[i4];
        float4 wv = ((const float4*)wgt)[i4];
        ((float4*)o)[i4] = make_float4((float)r0.x, (float)r0.y, (float)r0.z, (float)r0.w);
        ((float4*)(o + 2 * ARW_ROW_LEN))[i4] = wv;
    }
    if (i4 < (ARW_N_WALKERS * ARW_LOUT) / 4) {
        ((float4*)(o + 2 * ARW_ROW_LEN + ARW_N_EDGES))[i4] = make_float4(1.f, 1.f, 1.f, 1.f);
    }
}

extern "C" void kernel_launch(void* const* d_in, const int* in_sizes, int n_in,
                              void* d_out, int out_size, void* d_ws, size_t ws_size,
                              hipStream_t stream) {
    const int*   ei  = (const int*)d_in[0];
    const float* wgt = (const float*)d_in[1];
    const float* ru  = (const float*)d_in[2];
    int*   s = (int*)d_out;
    float* o = (float*)d_out;
    const int* row = ei;
    const int* col = ei + ARW_N_EDGES;

    arw16896_thist <<<ARW_NT, 1024, 0, stream>>>(row, s);
    arw16896_bscan2<<<ARW_NB, 1024, 0, stream>>>(s);
    arw16896_bbase <<<1, 256, 0, stream>>>(s);
    arw16896_part  <<<ARW_NT, 1024, 0, stream>>>(row, col, s);
    arw16896_pass2 <<<ARW_NB, 1024, 0, stream>>>(s);
    arw16896_walk  <<<(ARW_N_NODES + 255) / 256, 256, 0, stream>>>(ru, ei, s, o);
    arw16896_asm   <<<(ARW_N_EDGES / 4 + 255) / 256, 256, 0, stream>>>(ei, wgt, o);
}